// Round 9
// baseline (202.419 us; speedup 1.0000x reference)
//
#include <hip/hip_runtime.h>

typedef int v4i __attribute__((ext_vector_type(4)));

constexpr int Kdim = 4096;
constexpr int Ndim = 4096;
constexpr int MtotC = 8192;
constexpr int BM = 256;
constexpr int BN = 256;
constexpr int BKB = 128;          // K-bytes per LDS tile (2 halves of 64B)
constexpr int NT = Kdim / BKB;    // 32 K-tiles

// ---------------- pack int32 -> int8 (both tensors, one launch) ----------------
__global__ void pack_i32_to_i8(const int* __restrict__ xq, const int* __restrict__ wq,
                               signed char* __restrict__ x8, signed char* __restrict__ w8,
                               size_t nx4, size_t nw4) {
    size_t i = (size_t)blockIdx.x * blockDim.x + threadIdx.x;
    size_t stride = (size_t)gridDim.x * blockDim.x;
    size_t tot = nx4 + nw4;
    for (size_t j = i; j < tot; j += stride) {
        if (j < nx4) {
            const int4 v = ((const int4*)xq)[j];
            char4 c;
            c.x = (signed char)v.x; c.y = (signed char)v.y;
            c.z = (signed char)v.z; c.w = (signed char)v.w;
            ((char4*)x8)[j] = c;
        } else {
            const size_t k = j - nx4;
            const int4 v = ((const int4*)wq)[k];
            char4 c;
            c.x = (signed char)v.x; c.y = (signed char)v.y;
            c.z = (signed char)v.z; c.w = (signed char)v.w;
            ((char4*)w8)[k] = c;
        }
    }
}

// ---------------- int8 GEMM, 256x256 tile, 16x16x64 MFMA ----------------
// Flat K-tile, 2 barriers/K-tile (max cross-wave skew), two 12-read+32-MFMA
// halves separated by sched_barrier(0), setprio(1) around MFMA clusters.
// LDS: 2 bufs x 2 halves x (A 16KB + B 16KB) = 128KB.
// 16B-slot swizzle within a 64B row: slot' = slot ^ ((row>>1)&3)  (verified 0-conflict).
__global__ __launch_bounds__(512, 2) void i8gemm_kernel(
    const signed char* __restrict__ A,
    const signed char* __restrict__ W,
    const float* __restrict__ sx,
    const float* __restrict__ wsc,
    const float* __restrict__ bias,
    float* __restrict__ C)
{
    extern __shared__ signed char smem[];

    const int tid  = threadIdx.x;
    const int wave = tid >> 6;
    const int lane = tid & 63;
    const int wr = wave >> 2;     // 0..1  (128-row strip)
    const int wc = wave & 3;      // 0..3  (64-col strip)

    // XCD-aware swizzle: 8 regions of 8bm x 8bn
    const int xr_ = blockIdx.x & 7;
    const int idx = blockIdx.x >> 3;
    const int bm = ((xr_ & 3) * 8 + (idx & 7)) * BM;
    const int bn = ((xr_ >> 2) * 8 + (idx >> 3)) * BN;

    // ---- staging constants (per thread: 1 A + 1 B gload_lds per STG call) ----
    const int srow_in = wave * 16 + (lane >> 2);            // 0..127
    const int sslotp  = lane & 3;                           // LDS slot'
    const int gslot   = sslotp ^ ((srow_in >> 1) & 3);      // pre-inverse-swizzled global slot
    const signed char* Ag = A + (size_t)(bm + srow_in) * Kdim + gslot * 16;
    const signed char* Wg = W + (size_t)(bn + srow_in) * Kdim + gslot * 16;
    const int sdst = srow_in * 64 + sslotp * 16;            // within-half LDS offset

    // ---- fragment read constants (16x16x64: row/col = lane&15, 16B k-slot = lane>>4) ----
    const int frow = lane & 15;
    const int fsl  = lane >> 4;
    const int rsw  = ((fsl ^ ((frow >> 1) & 3)) << 4);      // swizzled 16B slot byte
    const int aro  = (wr * 128 + frow) * 64 + rsw;          // + f*1024 + half*32768
    const int bro  = 16384 + (wc * 64 + frow) * 64 + rsw;   // + g*1024 + half*32768

    v4i acc[8][4];
#pragma unroll
    for (int f = 0; f < 8; ++f)
#pragma unroll
        for (int g = 0; g < 4; ++g)
#pragma unroll
            for (int e = 0; e < 4; ++e) acc[f][g][e] = 0;

#define STG(KT, HALF, RB) do {                                                         \
    __builtin_amdgcn_global_load_lds(                                                  \
        (const __attribute__((address_space(1))) void*)(Ag + (size_t)(RB) * Kdim + (KT) * BKB + (HALF) * 64), \
        (__attribute__((address_space(3))) void*)(smem + ((KT) & 1) * 65536 + (HALF) * 32768 + (RB) * 64 + sdst), \
        16, 0, 0);                                                                     \
    __builtin_amdgcn_global_load_lds(                                                  \
        (const __attribute__((address_space(1))) void*)(Wg + (size_t)(RB) * Kdim + (KT) * BKB + (HALF) * 64), \
        (__attribute__((address_space(3))) void*)(smem + ((KT) & 1) * 65536 + (HALF) * 32768 + 16384 + (RB) * 64 + sdst), \
        16, 0, 0);                                                                     \
} while (0)

#define STAGEFULL(KT) do {                                                             \
    STG(KT, 0, 0);  STG(KT, 0, 128);                                                   \
    STG(KT, 1, 0);  STG(KT, 1, 128);                                                   \
} while (0)

#define BAR __builtin_amdgcn_s_barrier()

    // ---- prologue: stage tiles 0 and 1 fully (16 loads/thread); drain tile 0 ----
    STAGEFULL(0);
    STAGEFULL(1);
    asm volatile("s_waitcnt vmcnt(8)" ::: "memory");
    BAR;

    for (int u = 0; u < NT; ++u) {
        const signed char* bufb = smem + (u & 1) * 65536;

        // ---- half 0: 12 ds_read_b128 + 32 MFMA (compiler-interleaved lgkm) ----
        {
            v4i av[8], bv[4];
#pragma unroll
            for (int g = 0; g < 4; ++g) bv[g] = *(const v4i*)(bufb + bro + g * 1024);
#pragma unroll
            for (int f = 0; f < 8; ++f) av[f] = *(const v4i*)(bufb + aro + f * 1024);
            __builtin_amdgcn_s_setprio(1);
#pragma unroll
            for (int f = 0; f < 8; ++f)
#pragma unroll
                for (int g = 0; g < 4; ++g)
                    acc[f][g] = __builtin_amdgcn_mfma_i32_16x16x64_i8(av[f], bv[g], acc[f][g], 0, 0, 0);
            __builtin_amdgcn_s_setprio(0);
        }
        __builtin_amdgcn_sched_barrier(0);   // keep half-1 reads below half-0 MFMAs

        // ---- half 1: 12 ds_read_b128 + 32 MFMA ----
        {
            v4i av[8], bv[4];
#pragma unroll
            for (int g = 0; g < 4; ++g) bv[g] = *(const v4i*)(bufb + 32768 + bro + g * 1024);
#pragma unroll
            for (int f = 0; f < 8; ++f) av[f] = *(const v4i*)(bufb + 32768 + aro + f * 1024);
            __builtin_amdgcn_s_setprio(1);
#pragma unroll
            for (int f = 0; f < 8; ++f)
#pragma unroll
                for (int g = 0; g < 4; ++g)
                    acc[f][g] = __builtin_amdgcn_mfma_i32_16x16x64_i8(av[f], bv[g], acc[f][g], 0, 0, 0);
            __builtin_amdgcn_s_setprio(0);
        }

        BAR;   // all waves done reading buf[u&1] (every read feeds an MFMA above)

        if (u + 2 < NT) {
            STAGEFULL(u + 2);                                   // -> buf[u&1]
            asm volatile("s_waitcnt vmcnt(8)" ::: "memory");    // drain tile u+1 (old loads)
            BAR;
        } else if (u + 1 < NT) {
            asm volatile("s_waitcnt vmcnt(0)" ::: "memory");    // drain last tile
            BAR;
        }
    }

    // ---- epilogue: dequant + bias, fp32 store ----
    // 16x16 C/D map: col = lane&15, row = (lane>>4)*4 + reg
    const int orow0 = bm + wr * 128;
    const int ocol0 = bn + wc * 64;
    float wsv[4], bvv[4];
#pragma unroll
    for (int g = 0; g < 4; ++g) {
        const int col = ocol0 + g * 16 + frow;
        wsv[g] = wsc[col];
        bvv[g] = bias[col];
    }
#pragma unroll
    for (int f = 0; f < 8; ++f) {
#pragma unroll
        for (int jr = 0; jr < 4; ++jr) {
            const int row = orow0 + f * 16 + fsl * 4 + jr;
            const float s = sx[row];
#pragma unroll
            for (int g = 0; g < 4; ++g) {
                const int col = ocol0 + g * 16 + frow;
                C[(size_t)row * Ndim + col] = (float)acc[f][g][jr] * s * wsv[g] + bvv[g];
            }
        }
    }
#undef STG
#undef STAGEFULL
#undef BAR
}

extern "C" void kernel_launch(void* const* d_in, const int* in_sizes, int n_in,
                              void* d_out, int out_size, void* d_ws, size_t ws_size,
                              hipStream_t stream) {
    (void)in_sizes; (void)n_in; (void)out_size; (void)ws_size;
    const int*   x_q  = (const int*)d_in[0];
    const float* sx   = (const float*)d_in[1];
    const int*   w_q  = (const int*)d_in[2];
    const float* wsc  = (const float*)d_in[3];
    const float* bias = (const float*)d_in[4];
    float* out = (float*)d_out;

    signed char* x8 = (signed char*)d_ws;
    signed char* w8 = x8 + (size_t)MtotC * Kdim;

    const size_t nx = (size_t)MtotC * Kdim;   // 32 Mi
    const size_t nw = (size_t)Ndim * Kdim;    // 16 Mi

    pack_i32_to_i8<<<3072, 256, 0, stream>>>(x_q, w_q, x8, w8, nx / 4, nw / 4);

    static bool attr_set = false;
    if (!attr_set) {
        hipFuncSetAttribute((const void*)i8gemm_kernel,
                            hipFuncAttributeMaxDynamicSharedMemorySize, 131072);
        attr_set = true;
    }

    const int nwg = (MtotC / BM) * (Ndim / BN);  // 512
    i8gemm_kernel<<<nwg, 512, 131072, stream>>>(x8, w8, sx, wsc, bias, out);
}